// Round 6
// baseline (524.200 us; speedup 1.0000x reference)
//
#include <hip/hip_runtime.h>
#include <stdint.h>

// ============================================================================
// LUKE entity-aware attention block, MI355X gfx950, round 5.
// FP32 I/O, bf16 MFMA internals. Round-5 change (attention only):
//  - __launch_bounds__(256,3): LDS caps occupancy at 3 blocks/CU anyway, so
//    raise VGPR ceiling (~168) for deep load pipelining (was 68).
//  - QK^T computed as K@Q^T (m=key): P-store becomes ds_write_b64 (80->20
//    LDS writes/thread), mask load vectorized float4.
//  - manual 2-stage rolling pipelines for K (phase 1) and V (phase 3) loads.
// GEMM/LN/prep unchanged from r4.
// ============================================================================

#define B_ 16
#define S_ 512
#define E_ 128
#define T_ 640
#define D_ 768
#define H_ 12
#define DH_ 64
#define FF_ 3072
#define SCP_LD 664

typedef unsigned short u16;
typedef __bf16 bf16x8 __attribute__((ext_vector_type(8)));
typedef u16 u16x8 __attribute__((ext_vector_type(8)));
typedef u16 u16x4 __attribute__((ext_vector_type(4)));
typedef float f32x4 __attribute__((ext_vector_type(4)));

__device__ __forceinline__ float b2f(u16 v) {
  unsigned u = ((unsigned)v) << 16;
  return __builtin_bit_cast(float, u);
}
__device__ __forceinline__ u16 f2b(float f) {  // RNE
  unsigned u = __builtin_bit_cast(unsigned, f);
  u += 0x7FFFu + ((u >> 16) & 1u);
  return (u16)(u >> 16);
}

__device__ __forceinline__ void gl_lds16(const u16* g, u16* l) {
  __builtin_amdgcn_global_load_lds((__attribute__((address_space(1))) const void*)g,
                                   (__attribute__((address_space(3))) void*)l, 16, 0, 0);
}

// ============================================================================
// GEMM core: 128x128 tile, BK=64 as two BK=32 panels, 4 waves, 32 MFMA per
// barrier-pair. (unchanged from r3/r4)
// ============================================================================
__device__ __forceinline__ void gemm_core(
    const u16* __restrict__ A, const u16* __restrict__ Bt, int lda, int K,
    u16* As, u16* Bs, f32x4 (&acc)[4][4]) {
  const int tid = threadIdx.x;
  const int lane = tid & 63, wave = tid >> 6;
  const int wm = (wave & 1) << 6, wn = (wave >> 1) << 6;
  const int l15 = lane & 15, quad = lane >> 4;

  const int r0 = tid >> 2, c0 = (tid & 3) << 3;
  const u16* ga0 = A + (long long)r0 * lda + c0;
  const u16* ga1 = A + (long long)(r0 + 64) * lda + c0;
  const u16* gb0 = Bt + (long long)r0 * K + c0;
  const u16* gb1 = Bt + (long long)(r0 + 64) * K + c0;

  for (int k0 = 0; k0 < K; k0 += 64) {
    __syncthreads();
    gl_lds16(ga0 + k0, &As[tid * 8]);
    gl_lds16(ga1 + k0, &As[2048 + tid * 8]);
    gl_lds16(ga0 + k0 + 32, &As[4096 + tid * 8]);
    gl_lds16(ga1 + k0 + 32, &As[6144 + tid * 8]);
    gl_lds16(gb0 + k0, &Bs[tid * 8]);
    gl_lds16(gb1 + k0, &Bs[2048 + tid * 8]);
    gl_lds16(gb0 + k0 + 32, &Bs[4096 + tid * 8]);
    gl_lds16(gb1 + k0 + 32, &Bs[6144 + tid * 8]);
    __syncthreads();

#pragma unroll
    for (int p = 0; p < 2; p++) {
      bf16x8 af[4], bfr[4];
#pragma unroll
      for (int i = 0; i < 4; i++)
        af[i] = *(const bf16x8*)&As[p * 4096 + (wm + i * 16 + l15) * 32 + quad * 8];
#pragma unroll
      for (int i = 0; i < 4; i++)
        bfr[i] = *(const bf16x8*)&Bs[p * 4096 + (wn + i * 16 + l15) * 32 + quad * 8];
#pragma unroll
      for (int i = 0; i < 4; i++)
#pragma unroll
        for (int j = 0; j < 4; j++)
          acc[i][j] = __builtin_amdgcn_mfma_f32_16x16x32_bf16(af[i], bfr[j], acc[i][j], 0, 0, 0);
    }
  }
}

__device__ __forceinline__ void epi_store(
    f32x4 (&acc)[4][4], const u16* __restrict__ bias, u16* __restrict__ C,
    int m0, int n0, int ldc, bool gelu) {
  const int tid = threadIdx.x;
  const int lane = tid & 63, wave = tid >> 6;
  const int wm = (wave & 1) << 6, wn = (wave >> 1) << 6;
  const int l15 = lane & 15, quad = lane >> 4;
  float bv[4];
#pragma unroll
  for (int j = 0; j < 4; j++) bv[j] = b2f(bias[n0 + wn + j * 16 + l15]);
#pragma unroll
  for (int i = 0; i < 4; i++) {
    const int row = m0 + wm + i * 16 + quad * 4;
#pragma unroll
    for (int j = 0; j < 4; j++) {
      const int col = n0 + wn + j * 16 + l15;
#pragma unroll
      for (int r = 0; r < 4; r++) {
        float v = acc[i][j][r] + bv[j];
        if (gelu) v = 0.5f * v * (1.0f + erff(v * 0.70710678118654752f));
        C[(long long)(row + r) * ldc + col] = f2b(v);
      }
    }
  }
}

// MODE 0: plain C = A@Bt^T + bias ; MODE 1: merged KV ; MODE 2: merged Q
template <int MODE, bool GELU>
__global__ __launch_bounds__(256) void gemm_kernel(
    const u16* __restrict__ A, const u16* __restrict__ Bt0,
    const u16* __restrict__ Bt1, const u16* __restrict__ Bt2,
    const u16* __restrict__ Bt3, const u16* __restrict__ bias0,
    const u16* __restrict__ bias1, const u16* __restrict__ bias2,
    const u16* __restrict__ bias3, u16* __restrict__ C0, u16* __restrict__ C1,
    int lda, int ldc, int K, long long sA, long long sC) {
  __shared__ __align__(16) u16 As[8192];
  __shared__ __align__(16) u16 Bs[8192];

  const int m0 = blockIdx.x * 128;
  int n0;
  const u16 *Bt, *bias;
  u16* C;
  bool vstore = false;
  if (MODE == 0) {
    n0 = blockIdx.y * 128;
    Bt = Bt0; bias = bias0; C = C0;
  } else if (MODE == 1) {
    if (blockIdx.y < 6) { n0 = blockIdx.y * 128; Bt = Bt0; bias = bias0; C = C0; }
    else { n0 = (blockIdx.y - 6) * 128; Bt = Bt1; bias = bias1; C = C1; vstore = true; }
  } else {
    const bool isE = (blockIdx.x >= 4);
    if (blockIdx.y < 6) {
      n0 = blockIdx.y * 128;
      Bt = isE ? Bt1 : Bt0; bias = isE ? bias1 : bias0; C = C0;
    } else {
      n0 = (blockIdx.y - 6) * 128;
      Bt = isE ? Bt3 : Bt2; bias = isE ? bias3 : bias2; C = C1;
    }
  }

  const u16* Ab = A + (long long)blockIdx.z * sA + (long long)m0 * lda;
  C += (long long)blockIdx.z * sC;

  f32x4 acc[4][4] = {};
  gemm_core(Ab, Bt + (long long)n0 * K, lda, K, As, Bs, acc);

  if (MODE == 1 && vstore) {
    const int tid = threadIdx.x;
    const int lane = tid & 63, wave = tid >> 6;
    const int wm = (wave & 1) << 6, wn = (wave >> 1) << 6;
    const int l15 = lane & 15, quad = lane >> 4;
    float bv[4];
#pragma unroll
    for (int j = 0; j < 4; j++) bv[j] = b2f(bias[n0 + wn + j * 16 + l15]);
#pragma unroll
    for (int i = 0; i < 4; i++) {
      const int grow = m0 + wm + i * 16 + quad * 4;
      const int bb = grow / T_, tt = grow - bb * T_;
#pragma unroll
      for (int j = 0; j < 4; j++) {
        const int col = n0 + wn + j * 16 + l15;
        u16x4 pk;
#pragma unroll
        for (int r = 0; r < 4; r++) pk[r] = f2b(acc[i][j][r] + bv[j]);
        *(u16x4*)&C[(((long long)bb * H_ + (col >> 6)) * DH_ + (col & 63)) * T_ + tt] = pk;
      }
    }
  } else {
    epi_store(acc, bias, C, m0, n0, ldc, GELU);
  }
}

// ============================================================================
// Fused attention v4: 1D grid 3840, XCD swizzle (r4). Phase 1 computes
// S^T = K@Q^T so the 4 acc elems are consecutive KEYS -> single ds_write_b64
// per group; scp layout stays [q][key]. Rolling 2-stage pipelines on K and V
// loads; __launch_bounds__(256,3) frees VGPRs for them.
// ============================================================================
__global__ __launch_bounds__(256, 3) void attn_kernel(
    const u16* __restrict__ Qw, const u16* __restrict__ Qe,
    const u16* __restrict__ Kb, const u16* __restrict__ Vt,
    const float* __restrict__ mask, u16* __restrict__ ctx) {
  const int id = blockIdx.x;
  const int xcd = id & 7;
  const int slot = id >> 3;
  const int pl = slot / 20;
  const int qt = slot - pl * 20;
  const int pair = xcd * 24 + pl;
  const int b = pair / H_, h = pair - b * H_;
  const int q0 = qt * 32;

  __shared__ __align__(16) u16 scp[32 * SCP_LD];
  __shared__ float rsum[32];

  const int tid = threadIdx.x;
  const int lane = tid & 63, wave = tid >> 6;
  const int l15 = lane & 15, quad = lane >> 4;

  const long long bh = (long long)b * T_ * D_ + h * DH_;
  const long long bhV = ((long long)b * H_ + h) * DH_ * T_;

  // Q fragments: [q-group][w/e][k-half]  (B-operand, n = q)
  bf16x8 qf[2][2][2];
#pragma unroll
  for (int g = 0; g < 2; g++) {
    const u16* qwp = Qw + bh + (long long)(q0 + g * 16 + l15) * D_ + quad * 8;
    const u16* qep = Qe + bh + (long long)(q0 + g * 16 + l15) * D_ + quad * 8;
    qf[g][0][0] = *(const bf16x8*)(qwp);
    qf[g][0][1] = *(const bf16x8*)(qwp + 32);
    qf[g][1][0] = *(const bf16x8*)(qep);
    qf[g][1][1] = *(const bf16x8*)(qep + 32);
  }

  // ---- phase 1: S^T = K Q^T, rolling K pipeline -------------------------
  const float* mrow = mask + b * T_;
  const int kbase = wave * 160;
  bf16x8 kc0, kc1;
  f32x4 mc;
  {
    const u16* kp = Kb + bh + (long long)(kbase + l15) * D_ + quad * 8;
    kc0 = *(const bf16x8*)(kp);
    kc1 = *(const bf16x8*)(kp + 32);
    mc = *(const f32x4*)(mrow + kbase + quad * 4);
  }
#pragma unroll
  for (int i = 0; i < 10; i++) {
    const int key0 = kbase + i * 16;
    bf16x8 kn0, kn1;
    f32x4 mn;
    if (i < 9) {
      const u16* kp = Kb + bh + (long long)(key0 + 16 + l15) * D_ + quad * 8;
      kn0 = *(const bf16x8*)(kp);
      kn1 = *(const bf16x8*)(kp + 32);
      mn = *(const f32x4*)(mrow + key0 + 16 + quad * 4);
    }
    const int e = (key0 < S_) ? 0 : 1;  // wave-uniform
#pragma unroll
    for (int g = 0; g < 2; g++) {
      f32x4 a = {0.f, 0.f, 0.f, 0.f};
      a = __builtin_amdgcn_mfma_f32_16x16x32_bf16(kc0, qf[g][e][0], a, 0, 0, 0);
      a = __builtin_amdgcn_mfma_f32_16x16x32_bf16(kc1, qf[g][e][1], a, 0, 0, 0);
      // C: m=key -> quad*4+r, n=q -> l15  => 4 consecutive keys, one b64 store
      u16x4 pk;
#pragma unroll
      for (int r = 0; r < 4; r++) pk[r] = f2b(a[r] * 0.125f + mc[r]);
      *(u16x4*)&scp[(g * 16 + l15) * SCP_LD + key0 + quad * 4] = pk;
    }
    kc0 = kn0; kc1 = kn1; mc = mn;
  }
  __syncthreads();

  // ---- phase 2: softmax (vectorized, unnormalized; row sums kept) -------
  {
    const int row = tid >> 3, ck = tid & 7;
    float mx = -1e30f;
#pragma unroll
    for (int c = 0; c < 10; c++) {
      const u16x8 v = *(const u16x8*)&scp[row * SCP_LD + c * 64 + ck * 8];
#pragma unroll
      for (int e = 0; e < 8; e++) mx = fmaxf(mx, b2f(v[e]));
    }
#pragma unroll
    for (int d = 4; d; d >>= 1) mx = fmaxf(mx, __shfl_xor(mx, d, 8));
    float sum = 0.f;
#pragma unroll
    for (int c = 0; c < 10; c++) {
      u16* p = &scp[row * SCP_LD + c * 64 + ck * 8];
      const u16x8 v = *(const u16x8*)p;
      u16x8 o;
#pragma unroll
      for (int e = 0; e < 8; e++) {
        const float ex = __expf(b2f(v[e]) - mx);
        sum += ex;
        o[e] = f2b(ex);
      }
      *(u16x8*)p = o;
    }
#pragma unroll
    for (int d = 4; d; d >>= 1) sum += __shfl_xor(sum, d, 8);
    if (ck == 0) rsum[row] = sum;
  }
  __syncthreads();

  // ---- phase 3: ctx = P V via Vt, rolling V pipeline ---------------------
  f32x4 o0 = {0.f, 0.f, 0.f, 0.f}, o1 = {0.f, 0.f, 0.f, 0.f};
  const u16* vrow = Vt + bhV + (long long)(wave * 16 + l15) * T_;
  int ko = quad * 8;
  bf16x8 vc = *(const bf16x8*)(vrow + ko);
#pragma unroll
  for (int s = 0; s < 20; s++) {
    bf16x8 vn;
    if (s < 19) vn = *(const bf16x8*)(vrow + ko + 32);
    const bf16x8 p0 = *(const bf16x8*)&scp[l15 * SCP_LD + ko];
    const bf16x8 p1 = *(const bf16x8*)&scp[(16 + l15) * SCP_LD + ko];
    o0 = __builtin_amdgcn_mfma_f32_16x16x32_bf16(p0, vc, o0, 0, 0, 0);
    o1 = __builtin_amdgcn_mfma_f32_16x16x32_bf16(p1, vc, o1, 0, 0, 0);
    vc = vn;
    ko += 32;
  }

  u16* cp0 = ctx + bh + (long long)(q0 + quad * 4) * D_ + wave * 16 + l15;
#pragma unroll
  for (int r = 0; r < 4; r++) cp0[(long long)r * D_] = f2b(o0[r] / rsum[quad * 4 + r]);
  u16* cp1 = ctx + bh + (long long)(q0 + 16 + quad * 4) * D_ + wave * 16 + l15;
#pragma unroll
  for (int r = 0; r < 4; r++) cp1[(long long)r * D_] = f2b(o1[r] / rsum[16 + quad * 4 + r]);
}

// ============================================================================
// LayerNorm over D=768 with fused residual add.
// ============================================================================
template <int SPLIT>
__global__ __launch_bounds__(256) void ln_kernel(
    const u16* __restrict__ x, const u16* __restrict__ res,
    const u16* __restrict__ g, const u16* __restrict__ beta,
    void* __restrict__ out_) {
  const int row = blockIdx.x;
  const int tid = threadIdx.x;
  const u16* xp = x + (long long)row * D_;
  const u16* rp = res + (long long)row * D_;
  float v[3], s = 0.f, s2 = 0.f;
#pragma unroll
  for (int i = 0; i < 3; i++) {
    const int c = tid + i * 256;
    v[i] = b2f(xp[c]) + b2f(rp[c]);
    s += v[i];
    s2 += v[i] * v[i];
  }
#pragma unroll
  for (int d = 32; d; d >>= 1) {
    s += __shfl_xor(s, d, 64);
    s2 += __shfl_xor(s2, d, 64);
  }
  __shared__ float red[8];
  const int wave = tid >> 6;
  if ((tid & 63) == 0) { red[wave * 2] = s; red[wave * 2 + 1] = s2; }
  __syncthreads();
  s = red[0] + red[2] + red[4] + red[6];
  s2 = red[1] + red[3] + red[5] + red[7];
  const float mean = s * (1.f / 768.f);
  const float var = s2 * (1.f / 768.f) - mean * mean;
  const float rs = rsqrtf(var + 1e-12f);
  if (SPLIT) {
    float* out = (float*)out_;
    const int b = row / T_, t = row % T_;
    float* op = (t < S_) ? out + ((long long)b * S_ + t) * D_
                         : out + (long long)B_ * S_ * D_ + ((long long)b * E_ + (t - S_)) * D_;
#pragma unroll
    for (int i = 0; i < 3; i++) {
      const int c = tid + i * 256;
      op[c] = (v[i] - mean) * rs * b2f(g[c]) + b2f(beta[c]);
    }
  } else {
    u16* op = (u16*)out_ + (long long)row * D_;
#pragma unroll
    for (int i = 0; i < 3; i++) {
      const int c = tid + i * 256;
      op[c] = f2b((v[i] - mean) * rs * b2f(g[c]) + b2f(beta[c]));
    }
  }
}

__global__ __launch_bounds__(256) void transpose_kernel(
    const float* __restrict__ in, u16* __restrict__ out, int K, int N) {
  __shared__ u16 t[32][33];
  const int n0 = blockIdx.x * 32, k0 = blockIdx.y * 32;
  const int tx = threadIdx.x, ty = threadIdx.y;
#pragma unroll
  for (int i = 0; i < 4; i++)
    t[ty + i * 8][tx] = f2b(in[(long long)(k0 + ty + i * 8) * N + n0 + tx]);
  __syncthreads();
#pragma unroll
  for (int i = 0; i < 4; i++)
    out[(long long)(n0 + ty + i * 8) * K + k0 + tx] = t[tx][ty + i * 8];
}

struct T7 { const float* s[7]; u16* d[7]; };
__global__ __launch_bounds__(256) void transpose7_kernel(T7 a) {
  __shared__ u16 t[32][33];
  const float* in = a.s[blockIdx.z];
  u16* out = a.d[blockIdx.z];
  const int n0 = blockIdx.x * 32, k0 = blockIdx.y * 32;
  const int tx = threadIdx.x, ty = threadIdx.y;
#pragma unroll
  for (int i = 0; i < 4; i++)
    t[ty + i * 8][tx] = f2b(in[(long long)(k0 + ty + i * 8) * 768 + n0 + tx]);
  __syncthreads();
#pragma unroll
  for (int i = 0; i < 4; i++)
    out[(long long)(n0 + ty + i * 8) * 768 + k0 + tx] = t[tx][ty + i * 8];
}

__global__ __launch_bounds__(256) void concat_kernel(
    const float* __restrict__ w, const float* __restrict__ e, u16* __restrict__ x) {
  const long long i = (long long)(blockIdx.x * 256 + threadIdx.x) * 8;
  const long long NW = (long long)B_ * S_ * D_;
  const long long NE = (long long)B_ * E_ * D_;
  const long long SD = (long long)S_ * D_;
  const long long ED = (long long)E_ * D_;
  const long long TD = (long long)T_ * D_;
  const float* src;
  u16* dst;
  if (i < NW) {
    const long long b = i / SD, r = i % SD;
    src = w + i;
    dst = &x[b * TD + r];
  } else {
    const long long j = i - NW;
    if (j >= NE) return;
    const long long b = j / ED, r = j % ED;
    src = e + j;
    dst = &x[b * TD + SD + r];
  }
  const float4 f0 = *(const float4*)(src);
  const float4 f1 = *(const float4*)(src + 4);
  u16x8 o;
  o[0] = f2b(f0.x); o[1] = f2b(f0.y); o[2] = f2b(f0.z); o[3] = f2b(f0.w);
  o[4] = f2b(f1.x); o[5] = f2b(f1.y); o[6] = f2b(f1.z); o[7] = f2b(f1.w);
  *(u16x8*)dst = o;
}

struct CvtArgs { const float* src[13]; u16* dst[13]; int n[13]; };
__global__ __launch_bounds__(256) void cvt_vecs_kernel(CvtArgs a) {
  const int v = blockIdx.x;
  const float* s = a.src[v];
  u16* d = a.dst[v];
  const int n = a.n[v];
  for (int i = threadIdx.x; i < n; i += 256) d[i] = f2b(s[i]);
}

extern "C" void kernel_launch(void* const* d_in, const int* in_sizes, int n_in,
                              void* d_out, int out_size, void* d_ws, size_t ws_size,
                              hipStream_t stream) {
  (void)in_sizes; (void)n_in; (void)out_size; (void)ws_size;
  const float* word = (const float*)d_in[0];
  const float* ent = (const float*)d_in[1];
  const float* mask = (const float*)d_in[2];
  const float* W_q = (const float*)d_in[3];
  const float* b_q = (const float*)d_in[4];
  const float* W_k = (const float*)d_in[5];
  const float* b_k = (const float*)d_in[6];
  const float* W_v = (const float*)d_in[7];
  const float* b_v = (const float*)d_in[8];
  const float* W_w2e = (const float*)d_in[9];
  const float* b_w2e = (const float*)d_in[10];
  const float* W_e2w = (const float*)d_in[11];
  const float* b_e2w = (const float*)d_in[12];
  const float* W_e2e = (const float*)d_in[13];
  const float* b_e2e = (const float*)d_in[14];
  const float* W_ao = (const float*)d_in[15];
  const float* b_ao = (const float*)d_in[16];
  const float* g_ao = (const float*)d_in[17];
  const float* be_ao = (const float*)d_in[18];
  const float* W_i = (const float*)d_in[19];
  const float* b_i = (const float*)d_in[20];
  const float* W_o = (const float*)d_in[21];
  const float* b_o = (const float*)d_in[22];
  const float* g_o = (const float*)d_in[23];
  const float* be_o = (const float*)d_in[24];

  const size_t DD = (size_t)D_ * D_ * 2;
  const size_t DFF = (size_t)D_ * FF_ * 2;
  const size_t TD = (size_t)B_ * T_ * D_ * 2;
  size_t off = 0;
  char* base = (char*)d_ws;
  auto take = [&](size_t n) { void* p = base + off; off += n; return p; };
  u16* wqT = (u16*)take(DD);
  u16* wkT = (u16*)take(DD);
  u16* wvT = (u16*)take(DD);
  u16* ww2eT = (u16*)take(DD);
  u16* we2wT = (u16*)take(DD);
  u16* we2eT = (u16*)take(DD);
  u16* waoT = (u16*)take(DD);
  u16* wiT = (u16*)take(DFF);
  u16* woT = (u16*)take(DFF);
  u16* vecs = (u16*)take(2 * 16384);
  u16* xall = (u16*)take(TD);
  u16* qw = (u16*)take(TD);
  u16* qe = (u16*)take(TD);
  u16* kb = (u16*)take(TD);
  u16* vt = (u16*)take(TD);
  u16* ctxb = (u16*)take(TD);
  u16* inter = (u16*)take((size_t)B_ * T_ * FF_ * 2);
  u16* bq = vecs + 0 * 768;
  u16* bk = vecs + 1 * 768;
  u16* bv = vecs + 2 * 768;
  u16* bw2e = vecs + 3 * 768;
  u16* be2w = vecs + 4 * 768;
  u16* be2e = vecs + 5 * 768;
  u16* bao = vecs + 6 * 768;
  u16* gao = vecs + 7 * 768;
  u16* beao = vecs + 8 * 768;
  u16* bo = vecs + 9 * 768;
  u16* go = vecs + 10 * 768;
  u16* beo = vecs + 11 * 768;
  u16* bi = vecs + 12 * 768;  // 3072 elems
  u16* ao_raw = qw;
  u16* ao = kb;
  u16* out_raw = qe;

  CvtArgs ca;
  ca.src[0] = b_q;   ca.dst[0] = bq;   ca.n[0] = 768;
  ca.src[1] = b_k;   ca.dst[1] = bk;   ca.n[1] = 768;
  ca.src[2] = b_v;   ca.dst[2] = bv;   ca.n[2] = 768;
  ca.src[3] = b_w2e; ca.dst[3] = bw2e; ca.n[3] = 768;
  ca.src[4] = b_e2w; ca.dst[4] = be2w; ca.n[4] = 768;
  ca.src[5] = b_e2e; ca.dst[5] = be2e; ca.n[5] = 768;
  ca.src[6] = b_ao;  ca.dst[6] = bao;  ca.n[6] = 768;
  ca.src[7] = g_ao;  ca.dst[7] = gao;  ca.n[7] = 768;
  ca.src[8] = be_ao; ca.dst[8] = beao; ca.n[8] = 768;
  ca.src[9] = b_o;   ca.dst[9] = bo;   ca.n[9] = 768;
  ca.src[10] = g_o;  ca.dst[10] = go;  ca.n[10] = 768;
  ca.src[11] = be_o; ca.dst[11] = beo; ca.n[11] = 768;
  ca.src[12] = b_i;  ca.dst[12] = bi;  ca.n[12] = 3072;
  cvt_vecs_kernel<<<13, 256, 0, stream>>>(ca);

  T7 t7;
  t7.s[0] = W_q;   t7.d[0] = wqT;
  t7.s[1] = W_k;   t7.d[1] = wkT;
  t7.s[2] = W_v;   t7.d[2] = wvT;
  t7.s[3] = W_w2e; t7.d[3] = ww2eT;
  t7.s[4] = W_e2w; t7.d[4] = we2wT;
  t7.s[5] = W_e2e; t7.d[5] = we2eT;
  t7.s[6] = W_ao;  t7.d[6] = waoT;
  const dim3 tb(32, 8);
  transpose7_kernel<<<dim3(24, 24, 7), tb, 0, stream>>>(t7);
  transpose_kernel<<<dim3(96, 24), tb, 0, stream>>>(W_i, wiT, 768, 3072);
  transpose_kernel<<<dim3(24, 96), tb, 0, stream>>>(W_o, woT, 3072, 768);
  concat_kernel<<<3840, 256, 0, stream>>>(word, ent, xall);

  const long long TDs = (long long)T_ * D_;
  gemm_kernel<1, false><<<dim3(80, 12, 1), 256, 0, stream>>>(
      xall, wkT, wvT, nullptr, nullptr, bk, bv, nullptr, nullptr, kb, vt,
      768, 768, 768, 0, 0);
  gemm_kernel<2, false><<<dim3(5, 12, 16), 256, 0, stream>>>(
      xall, wqT, we2wT, ww2eT, we2eT, bq, be2w, bw2e, be2e, qw, qe,
      768, 768, 768, TDs, TDs);

  attn_kernel<<<3840, 256, 0, stream>>>(qw, qe, kb, vt, mask, ctxb);

  gemm_kernel<0, false><<<dim3(80, 6, 1), 256, 0, stream>>>(
      ctxb, waoT, nullptr, nullptr, nullptr, bao, nullptr, nullptr, nullptr,
      ao_raw, nullptr, 768, 768, 768, 0, 0);
  ln_kernel<0><<<10240, 256, 0, stream>>>(ao_raw, xall, gao, beao, ao);
  gemm_kernel<0, true><<<dim3(80, 24, 1), 256, 0, stream>>>(
      ao, wiT, nullptr, nullptr, nullptr, bi, nullptr, nullptr, nullptr,
      inter, nullptr, 768, 3072, 768, 0, 0);
  gemm_kernel<0, false><<<dim3(80, 6, 1), 256, 0, stream>>>(
      inter, woT, nullptr, nullptr, nullptr, bo, nullptr, nullptr, nullptr,
      out_raw, nullptr, 3072, 768, 3072, 0, 0);
  ln_kernel<1><<<10240, 256, 0, stream>>>(out_raw, ao, go, beo, d_out);
}